// Round 5
// baseline (99.493 us; speedup 1.0000x reference)
//
#include <hip/hip_runtime.h>

#define LSEQ 4096
#define NB 4
#define ROWS_PER_BLOCK 8   // 8*4096 rows / 8 = 4096 blocks = 16/CU (2 generations)

typedef float f32x4 __attribute__((ext_vector_type(4)));

// Single fused kernel: each block fills 8 consecutive output rows (128 KB).
// Row layout: row = c*4096 + i.
//   c < 4 : out[row][j] = one_hot[i, c]     (row-constant)
//   c >= 4: out[row][j] = one_hot[j, c-4]   (identical for all rows; read once)
__global__ __launch_bounds__(256) void fill_out(const float* __restrict__ oh,
                                                float* __restrict__ out) {
    int row0 = blockIdx.x * ROWS_PER_BLOCK;
    int c = row0 >> 12;                 // channel, uniform across block
    int t = threadIdx.x;
    f32x4* obase = reinterpret_cast<f32x4*>(out) + (size_t)row0 * (LSEQ / 4);

    if (c < NB) {
        // Precompute the 8 row-constants first (uniform addrs -> scalar loads),
        // so the 8*64 stores afterwards have no outstanding memory deps.
        float rv[ROWS_PER_BLOCK];
#pragma unroll
        for (int r = 0; r < ROWS_PER_BLOCK; ++r) {
            int i = (row0 + r) & (LSEQ - 1);
            rv[r] = oh[i * NB + c];
        }
#pragma unroll
        for (int r = 0; r < ROWS_PER_BLOCK; ++r) {
            f32x4 v4 = {rv[r], rv[r], rv[r], rv[r]};
            f32x4* orow = obase + (size_t)r * (LSEQ / 4);
#pragma unroll
            for (int k = 0; k < 4; ++k)
                orow[t + 256 * k] = v4;
        }
    } else {
        int b = c - NB;
        // Gather this thread's 16 source floats once (L2-resident), then
        // stream 8 identical row-copies.
        f32x4 vals[4];
#pragma unroll
        for (int k = 0; k < 4; ++k) {
            int j0 = 4 * (t + 256 * k);
            f32x4 v;
            v.x = oh[(j0 + 0) * NB + b];
            v.y = oh[(j0 + 1) * NB + b];
            v.z = oh[(j0 + 2) * NB + b];
            v.w = oh[(j0 + 3) * NB + b];
            vals[k] = v;
        }
#pragma unroll
        for (int r = 0; r < ROWS_PER_BLOCK; ++r) {
            f32x4* orow = obase + (size_t)r * (LSEQ / 4);
#pragma unroll
            for (int k = 0; k < 4; ++k)
                orow[t + 256 * k] = vals[k];
        }
    }
}

extern "C" void kernel_launch(void* const* d_in, const int* in_sizes, int n_in,
                              void* d_out, int out_size, void* d_ws, size_t ws_size,
                              hipStream_t stream) {
    const float* one_hot = (const float*)d_in[0];   // [4096, 4] f32
    float* out = (float*)d_out;                     // [1, 8, 4096, 4096] f32

    fill_out<<<(8 * LSEQ) / ROWS_PER_BLOCK, 256, 0, stream>>>(one_hot, out);
}